// Round 7
// baseline (581.449 us; speedup 1.0000x reference)
//
#include <hip/hip_runtime.h>
#include <hip/hip_fp16.h>
#include <math.h>

#define N_NODES 100000
#define E_EDGES 1600000
#define F_IN 128
#define D_DIM 16
#define H_HEADS 8
#define HD 128
#define NEG_SLOPE 0.2f

#define SCAN_BLOCKS 256
#define SCAN_T 256
#define SCAN_CH ((N_NODES + SCAN_BLOCKS - 1) / SCAN_BLOCKS)   // 391

#define NTILES ((N_NODES + 63) / 64)        // 1563 node-tiles of 64

// ---------------------------------------------------------------------------
// Embedding: h0[n, 0..15] = x[n, :] @ W_emb + b_emb
// ---------------------------------------------------------------------------
__global__ __launch_bounds__(256) void embed_kernel(
        const float* __restrict__ x, const float* __restrict__ W,
        const float* __restrict__ b, float* __restrict__ h0) {
    __shared__ float Ws[F_IN * D_DIM];   // 8 KB
    __shared__ float bs[D_DIM];
    __shared__ float xs[16][F_IN + 1];
    int t = threadIdx.x;
    for (int i = t; i < F_IN * D_DIM; i += 256) Ws[i] = W[i];
    if (t < D_DIM) bs[t] = b[t];
    __syncthreads();
    for (int base = blockIdx.x * 16; base < N_NODES; base += gridDim.x * 16) {
        int cnt = min(16, N_NODES - base);
        __syncthreads();
        for (int i = t; i < cnt * F_IN; i += 256) {
            int nn = i >> 7, k = i & 127;
            xs[nn][k] = x[(size_t)(base + nn) * F_IN + k];
        }
        __syncthreads();
        int nn = t >> 4, c = t & 15;
        if (nn < cnt) {
            float a0 = 0.f, a1 = 0.f, a2 = 0.f, a3 = 0.f;
            #pragma unroll
            for (int k = 0; k < F_IN; k += 4) {
                a0 += xs[nn][k + 0] * Ws[(k + 0) * D_DIM + c];
                a1 += xs[nn][k + 1] * Ws[(k + 1) * D_DIM + c];
                a2 += xs[nn][k + 2] * Ws[(k + 2) * D_DIM + c];
                a3 += xs[nn][k + 3] * Ws[(k + 3) * D_DIM + c];
            }
            h0[(size_t)(base + nn) * D_DIM + c] = (a0 + a1) + (a2 + a3) + bs[c];
        }
    }
}

// ---------------------------------------------------------------------------
// Node transform as register-tiled GEMM: [N,K] @ [K,128] -> g (fp16), + attn
// dots (fp32, computed from fp32 accumulators before rounding).
// ---------------------------------------------------------------------------
template<int K>
__global__ __launch_bounds__(256) void transform_gemm_kernel(
        const float* __restrict__ h, const float* __restrict__ W,
        const float* __restrict__ att_s, const float* __restrict__ att_d,
        __half* __restrict__ g, float* __restrict__ a_src, float* __restrict__ a_dst) {
    __shared__ float Ws[K][64];          // K=128: 32 KB, K=16: 4 KB
    __shared__ float hs[64][K + 4];      // pad +4 floats: break row-bank stack
    int t = threadIdx.x;
    int cq = t & 15;                     // channel quad within half (0..15)
    int nq = t >> 4;                     // node quad (0..15)
    constexpr int KSH = (K == 128) ? 7 : 4;

    for (int item = blockIdx.x; item < NTILES * 2; item += gridDim.x) {
        int tile = item >> 1;
        int coff = (item & 1) << 6;                 // 0 or 64
        int nbase = tile << 6;
        __syncthreads();                            // protect prev iter reads
        // stage W column-half: K x 64
        for (int i = t; i < K * 64; i += 256)
            Ws[i >> 6][i & 63] = W[(size_t)(i >> 6) * HD + coff + (i & 63)];
        // stage 64 h rows (clamped in tail tile)
        for (int i = t; i < (K << 6); i += 256) {
            int r = i >> KSH, k = i & (K - 1);
            int n = nbase + r; if (n >= N_NODES) n = N_NODES - 1;
            hs[r][k] = h[(size_t)n * K + k];
        }
        __syncthreads();

        float acc[4][4] = {{0.f}};
        #pragma unroll 2
        for (int k = 0; k < K; k += 4) {
            float4 w0 = *(const float4*)&Ws[k + 0][cq << 2];
            float4 w1 = *(const float4*)&Ws[k + 1][cq << 2];
            float4 w2 = *(const float4*)&Ws[k + 2][cq << 2];
            float4 w3 = *(const float4*)&Ws[k + 3][cq << 2];
            #pragma unroll
            for (int j = 0; j < 4; ++j) {
                float4 hv = *(const float4*)&hs[(nq << 2) + j][k];
                acc[j][0] += hv.x * w0.x + hv.y * w1.x + hv.z * w2.x + hv.w * w3.x;
                acc[j][1] += hv.x * w0.y + hv.y * w1.y + hv.z * w2.y + hv.w * w3.y;
                acc[j][2] += hv.x * w0.z + hv.y * w1.z + hv.z * w2.z + hv.w * w3.z;
                acc[j][3] += hv.x * w0.w + hv.y * w1.w + hv.z * w2.w + hv.w * w3.w;
            }
        }

        int c0 = coff + (cq << 2);
        float as0 = att_s[c0], as1 = att_s[c0 + 1], as2 = att_s[c0 + 2], as3 = att_s[c0 + 3];
        float ad0 = att_d[c0], ad1 = att_d[c0 + 1], ad2 = att_d[c0 + 2], ad3 = att_d[c0 + 3];
        int head = c0 >> 4;
        #pragma unroll
        for (int j = 0; j < 4; ++j) {
            int n = nbase + (nq << 2) + j;
            float ps = acc[j][0] * as0 + acc[j][1] * as1 + acc[j][2] * as2 + acc[j][3] * as3;
            float pd = acc[j][0] * ad0 + acc[j][1] * ad1 + acc[j][2] * ad2 + acc[j][3] * ad3;
            ps += __shfl_xor(ps, 1); ps += __shfl_xor(ps, 2);
            pd += __shfl_xor(pd, 1); pd += __shfl_xor(pd, 2);
            if (n < N_NODES) {
                union { __half2 h2[2]; uint2 u; } pk;
                pk.h2[0] = __floats2half2_rn(acc[j][0], acc[j][1]);
                pk.h2[1] = __floats2half2_rn(acc[j][2], acc[j][3]);
                *(uint2*)&g[(size_t)n * HD + c0] = pk.u;
                if ((cq & 3) == 0) {
                    a_src[(size_t)n * H_HEADS + head] = ps;
                    a_dst[(size_t)n * H_HEADS + head] = pd;
                }
            }
        }
    }
}

// ---------------------------------------------------------------------------
// CSR build: histogram -> 3-phase multi-block scan -> scatter.
// ---------------------------------------------------------------------------
__global__ __launch_bounds__(256) void hist_kernel(
        const int* __restrict__ ei, int* __restrict__ deg) {
    int e = blockIdx.x * 256 + threadIdx.x;
    if (e < E_EDGES) atomicAdd(&deg[ei[E_EDGES + e]], 1);
}

__global__ __launch_bounds__(SCAN_T) void block_sum_kernel(
        const int* __restrict__ deg, int* __restrict__ bsum) {
    int b = blockIdx.x, t = threadIdx.x;
    int lo = b * SCAN_CH, hi = min(lo + SCAN_CH, N_NODES);
    int s = 0;
    for (int i = lo + t; i < hi; i += SCAN_T) s += deg[i];
    #pragma unroll
    for (int m = 1; m < 64; m <<= 1) s += __shfl_xor(s, m);
    __shared__ int ws[SCAN_T / 64];
    if ((t & 63) == 0) ws[t >> 6] = s;
    __syncthreads();
    if (t == 0) {
        int tot = 0;
        #pragma unroll
        for (int w = 0; w < SCAN_T / 64; ++w) tot += ws[w];
        bsum[b] = tot;
    }
}

__global__ __launch_bounds__(SCAN_BLOCKS) void offset_scan_kernel(
        const int* __restrict__ bsum, int* __restrict__ boff) {
    __shared__ int tmp[SCAN_BLOCKS];
    int t = threadIdx.x;
    int v = bsum[t];
    tmp[t] = v;
    __syncthreads();
    int val = v;
    for (int off = 1; off < SCAN_BLOCKS; off <<= 1) {
        int o = (t >= off) ? tmp[t - off] : 0;
        __syncthreads();
        val += o;
        tmp[t] = val;
        __syncthreads();
    }
    boff[t] = val - v;    // exclusive
}

__global__ __launch_bounds__(SCAN_T) void row_ptr_kernel(
        const int* __restrict__ deg, const int* __restrict__ boff,
        int* __restrict__ row_ptr, int* __restrict__ fill) {
    int b = blockIdx.x, t = threadIdx.x;
    int lo = b * SCAN_CH, hi = min(lo + SCAN_CH, N_NODES);
    __shared__ int tmp[SCAN_T];
    __shared__ int carry;
    if (t == 0) carry = boff[b];
    __syncthreads();
    for (int base = lo; base < hi; base += SCAN_T) {
        int i = base + t;
        int v = (i < hi) ? deg[i] : 0;
        tmp[t] = v;
        __syncthreads();
        int val = v;
        for (int off = 1; off < SCAN_T; off <<= 1) {
            int o = (t >= off) ? tmp[t - off] : 0;
            __syncthreads();
            val += o;
            tmp[t] = val;
            __syncthreads();
        }
        int excl = val - v + carry;
        if (i < hi) { row_ptr[i] = excl; fill[i] = excl; }
        __syncthreads();
        if (t == SCAN_T - 1) carry = carry + val;
        __syncthreads();
    }
    if (b == SCAN_BLOCKS - 1 && t == 0) row_ptr[N_NODES] = carry;  // == E
}

__global__ __launch_bounds__(256) void scatter_kernel(
        const int* __restrict__ ei, int* __restrict__ fill,
        int* __restrict__ col) {
    int e = blockIdx.x * 256 + threadIdx.x;
    if (e < E_EDGES) {
        int d = ei[E_EDGES + e];
        int p = atomicAdd(&fill[d], 1);
        col[p] = ei[e];
    }
}

// ---------------------------------------------------------------------------
// Fused GAT aggregation over CSR: one wave per dst node, no atomics.
// Lane layout: grp = lane>>4 (edge group 0..3), sub = lane&15 (channel slice,
// channels 8*sub..8*sub+7, all within head sub>>1). Per iteration the wave
// processes 4 edges with ONE dwordx4 g-load (16B/lane = 1KB), unrolled x2.
// Self-loop added after the cross-group shfl reduction.
// ---------------------------------------------------------------------------
template<bool FUSE>
__global__ __launch_bounds__(256) void gat_aggr_csr_kernel(
        const int* __restrict__ row_ptr, const int* __restrict__ col,
        const float* __restrict__ a_src, const float* __restrict__ a_dst,
        const __half* __restrict__ g, const float* __restrict__ bias,
        float* __restrict__ out,
        const float* __restrict__ Wy1, const float* __restrict__ by1,
        const float* __restrict__ Wy0, const float* __restrict__ by0,
        const float* __restrict__ Wc1, const float* __restrict__ bc1,
        const float* __restrict__ Wc2, const float* __restrict__ bc2) {
    int wv = threadIdx.x >> 6, lane = threadIdx.x & 63;
    int d = blockIdx.x * 4 + wv;
    if (d >= N_NODES) return;
    int grp = lane >> 4;                 // edge group
    int sub = lane & 15;                 // channel slice
    int hh  = sub >> 1;                  // head 0..7
    float ad = a_dst[d * 8 + hh];

    float acc[8] = {0.f, 0.f, 0.f, 0.f, 0.f, 0.f, 0.f, 0.f};
    float den = 0.f;
    int i0 = row_ptr[d], end = row_ptr[d + 1];

    #define EDGE_BODY(IDX)                                                   \
    {                                                                        \
        int idx = (IDX);                                                     \
        int s = col[idx < end ? idx : end - 1];                              \
        float a = a_src[s * 8 + hh] + ad;                                    \
        a = (a > 0.f) ? a : NEG_SLOPE * a;                                   \
        float w = (idx < end) ? __expf(a) : 0.f;                             \
        uint4 rv = *(const uint4*)(g + (size_t)s * HD + (sub << 3));         \
        float2 f0 = __half22float2(*(__half2*)&rv.x);                        \
        float2 f1 = __half22float2(*(__half2*)&rv.y);                        \
        float2 f2 = __half22float2(*(__half2*)&rv.z);                        \
        float2 f3 = __half22float2(*(__half2*)&rv.w);                        \
        acc[0] += w * f0.x; acc[1] += w * f0.y;                              \
        acc[2] += w * f1.x; acc[3] += w * f1.y;                              \
        acc[4] += w * f2.x; acc[5] += w * f2.y;                              \
        acc[6] += w * f3.x; acc[7] += w * f3.y;                              \
        den += w;                                                            \
    }

    for (int i = i0; i < end; i += 8) {
        EDGE_BODY(i + grp);
        EDGE_BODY(i + 4 + grp);
    }
    #undef EDGE_BODY

    // cross-group reduction: sum the 4 edge groups
    #pragma unroll
    for (int k = 0; k < 8; ++k) {
        acc[k] += __shfl_xor(acc[k], 16);
        acc[k] += __shfl_xor(acc[k], 32);
    }
    den += __shfl_xor(den, 16);
    den += __shfl_xor(den, 32);

    // self loop (identical in all lanes of same sub; added ONCE, post-reduce)
    {
        float a = a_src[d * 8 + hh] + ad;
        a = (a > 0.f) ? a : NEG_SLOPE * a;
        float w = __expf(a);
        uint4 rv = *(const uint4*)(g + (size_t)d * HD + (sub << 3));
        float2 f0 = __half22float2(*(__half2*)&rv.x);
        float2 f1 = __half22float2(*(__half2*)&rv.y);
        float2 f2 = __half22float2(*(__half2*)&rv.z);
        float2 f3 = __half22float2(*(__half2*)&rv.w);
        acc[0] += w * f0.x; acc[1] += w * f0.y;
        acc[2] += w * f1.x; acc[3] += w * f1.y;
        acc[4] += w * f2.x; acc[5] += w * f2.y;
        acc[6] += w * f3.x; acc[7] += w * f3.y;
        den += w;
    }

    float inv = 1.f / (den + 1e-16f);
    int c0 = sub << 3;
    float h[8];
    #pragma unroll
    for (int k = 0; k < 8; ++k) h[k] = acc[k] * inv + bias[c0 + k];

    if (!FUSE) {
        // groups 0 and 1 write the two float4 halves (other groups duplicate)
        if (grp == 0) *(float4*)&out[(size_t)d * HD + c0] =
            make_float4(h[0], h[1], h[2], h[3]);
        else if (grp == 1) *(float4*)&out[(size_t)d * HD + c0 + 4] =
            make_float4(h[4], h[5], h[6], h[7]);
    } else {
        // redistribute to (2l, 2l+1)-per-lane layout, then fused heads
        int src = lane >> 2;             // source lane (sub of owner, group 0)
        float t0 = __shfl(h[0], src), t2 = __shfl(h[2], src);
        float t4 = __shfl(h[4], src), t6 = __shfl(h[6], src);
        float t1 = __shfl(h[1], src), t3 = __shfl(h[3], src);
        float t5 = __shfl(h[5], src), t7 = __shfl(h[7], src);
        int m = lane & 3;
        float hA = (m == 0) ? t0 : (m == 1) ? t2 : (m == 2) ? t4 : t6;
        float hB = (m == 0) ? t1 : (m == 1) ? t3 : (m == 2) ? t5 : t7;
        int cc = lane << 1;
        float p = hA * (Wy1[cc] - Wy0[cc]) + hB * (Wy1[cc + 1] - Wy0[cc + 1]);
        #pragma unroll
        for (int mm = 1; mm < 64; mm <<= 1) p += __shfl_xor(p, mm);
        float acc2 = 0.f;
        #pragma unroll
        for (int j = 0; j < D_DIM; ++j) {
            float q = hA * Wc1[cc * D_DIM + j] + hB * Wc1[(cc + 1) * D_DIM + j];
            #pragma unroll
            for (int mm = 1; mm < 64; mm <<= 1) q += __shfl_xor(q, mm);
            float z = q + bc1[j];
            z = (z > 0.f) ? z : 0.f;
            acc2 += z * Wc2[j];
        }
        if (lane == 0) {
            out[d] = p + by1[0] - by0[0];
            out[N_NODES + d] = 1.f / (1.f + __expf(-(acc2 + bc2[0])));
        }
    }
}

// ---------------------------------------------------------------------------
extern "C" void kernel_launch(void* const* d_in, const int* in_sizes, int n_in,
                              void* d_out, int out_size, void* d_ws, size_t ws_size,
                              hipStream_t stream) {
    const float* x     = (const float*)d_in[0];
    const int*   ei    = (const int*)  d_in[1];
    const float* W_emb = (const float*)d_in[2];
    const float* b_emb = (const float*)d_in[3];
    const float* W0    = (const float*)d_in[4];
    const float* as0   = (const float*)d_in[5];
    const float* ad0   = (const float*)d_in[6];
    const float* b0    = (const float*)d_in[7];
    const float* W1    = (const float*)d_in[8];
    const float* as1   = (const float*)d_in[9];
    const float* ad1   = (const float*)d_in[10];
    const float* b1    = (const float*)d_in[11];
    const float* Wy1   = (const float*)d_in[12];
    const float* by1   = (const float*)d_in[13];
    const float* Wy0   = (const float*)d_in[14];
    const float* by0   = (const float*)d_in[15];
    const float* Wc1   = (const float*)d_in[16];
    const float* bc1   = (const float*)d_in[17];
    const float* Wc2   = (const float*)d_in[18];
    const float* bc2   = (const float*)d_in[19];
    float* out = (float*)d_out;

    float* ws    = (float*)d_ws;
    __half* gH   = (__half*)ws;                          // N*128 halves (25.6MB)
    float* bufH  = (float*)(ws + (size_t)N_NODES * HD / 2 + 64);  // N*128 f32
    float* h0    = bufH + (size_t)N_NODES * HD;          // N*16
    float* a_s   = h0   + (size_t)N_NODES * D_DIM;       // N*8
    float* a_d   = a_s  + (size_t)N_NODES * H_HEADS;     // N*8
    int*   deg     = (int*)(a_d + (size_t)N_NODES * H_HEADS);  // N
    int*   fill    = deg + N_NODES;                            // N
    int*   row_ptr = fill + N_NODES;                           // N+1
    int*   bsum    = row_ptr + (N_NODES + 1);                  // 256
    int*   boff    = bsum + SCAN_BLOCKS;                       // 256
    int*   col     = boff + SCAN_BLOCKS;                       // E

    int edgeBlocks = (E_EDGES + 255) / 256;
    int aggrBlocks = (N_NODES + 3) / 4;

    // ----- CSR build (once; reused by both layers) -----
    hipMemsetAsync(deg, 0, (size_t)N_NODES * sizeof(int), stream);
    hipLaunchKernelGGL(hist_kernel, dim3(edgeBlocks), dim3(256), 0, stream, ei, deg);
    hipLaunchKernelGGL(block_sum_kernel, dim3(SCAN_BLOCKS), dim3(SCAN_T), 0, stream,
                       deg, bsum);
    hipLaunchKernelGGL(offset_scan_kernel, dim3(1), dim3(SCAN_BLOCKS), 0, stream,
                       bsum, boff);
    hipLaunchKernelGGL(row_ptr_kernel, dim3(SCAN_BLOCKS), dim3(SCAN_T), 0, stream,
                       deg, boff, row_ptr, fill);
    hipLaunchKernelGGL(scatter_kernel, dim3(edgeBlocks), dim3(256), 0, stream,
                       ei, fill, col);

    // ----- Embedding -----
    hipLaunchKernelGGL(embed_kernel, dim3(512), dim3(256), 0, stream,
                       x, W_emb, b_emb, h0);

    // ----- GAT layer 0 (K = 16) -----
    hipLaunchKernelGGL(transform_gemm_kernel<16>, dim3(2048), dim3(256), 0, stream,
                       h0, W0, as0, ad0, gH, a_s, a_d);
    hipLaunchKernelGGL(gat_aggr_csr_kernel<false>, dim3(aggrBlocks), dim3(256), 0, stream,
                       row_ptr, col, a_s, a_d, gH, b0, bufH,
                       (const float*)nullptr, (const float*)nullptr,
                       (const float*)nullptr, (const float*)nullptr,
                       (const float*)nullptr, (const float*)nullptr,
                       (const float*)nullptr, (const float*)nullptr);

    // ----- GAT layer 1 (K = 128) + fused heads -----
    hipLaunchKernelGGL(transform_gemm_kernel<128>, dim3(1024), dim3(256), 0, stream,
                       bufH, W1, as1, ad1, gH, a_s, a_d);
    hipLaunchKernelGGL(gat_aggr_csr_kernel<true>, dim3(aggrBlocks), dim3(256), 0, stream,
                       row_ptr, col, a_s, a_d, gH, b1, out,
                       Wy1, by1, Wy0, by0, Wc1, bc1, Wc2, bc2);
}

// Round 8
// 573.451 us; speedup vs baseline: 1.0139x; 1.0139x over previous
//
#include <hip/hip_runtime.h>
#include <hip/hip_fp16.h>
#include <math.h>

#define N_NODES 100000
#define E_EDGES 1600000
#define F_IN 128
#define D_DIM 16
#define H_HEADS 8
#define HD 128
#define NEG_SLOPE 0.2f

#define SCAN_BLOCKS 256
#define SCAN_T 256
#define SCAN_CH ((N_NODES + SCAN_BLOCKS - 1) / SCAN_BLOCKS)   // 391

#define NTILES ((N_NODES + 63) / 64)        // 1563 node-tiles of 64

// ---------------------------------------------------------------------------
// Embedding: h0[n, 0..15] = x[n, :] @ W_emb + b_emb
// ---------------------------------------------------------------------------
__global__ __launch_bounds__(256) void embed_kernel(
        const float* __restrict__ x, const float* __restrict__ W,
        const float* __restrict__ b, float* __restrict__ h0) {
    __shared__ float Ws[F_IN * D_DIM];   // 8 KB
    __shared__ float bs[D_DIM];
    __shared__ float xs[16][F_IN + 1];
    int t = threadIdx.x;
    for (int i = t; i < F_IN * D_DIM; i += 256) Ws[i] = W[i];
    if (t < D_DIM) bs[t] = b[t];
    __syncthreads();
    for (int base = blockIdx.x * 16; base < N_NODES; base += gridDim.x * 16) {
        int cnt = min(16, N_NODES - base);
        __syncthreads();
        for (int i = t; i < cnt * F_IN; i += 256) {
            int nn = i >> 7, k = i & 127;
            xs[nn][k] = x[(size_t)(base + nn) * F_IN + k];
        }
        __syncthreads();
        int nn = t >> 4, c = t & 15;
        if (nn < cnt) {
            float a0 = 0.f, a1 = 0.f, a2 = 0.f, a3 = 0.f;
            #pragma unroll
            for (int k = 0; k < F_IN; k += 4) {
                a0 += xs[nn][k + 0] * Ws[(k + 0) * D_DIM + c];
                a1 += xs[nn][k + 1] * Ws[(k + 1) * D_DIM + c];
                a2 += xs[nn][k + 2] * Ws[(k + 2) * D_DIM + c];
                a3 += xs[nn][k + 3] * Ws[(k + 3) * D_DIM + c];
            }
            h0[(size_t)(base + nn) * D_DIM + c] = (a0 + a1) + (a2 + a3) + bs[c];
        }
    }
}

// ---------------------------------------------------------------------------
// Node transform as register-tiled GEMM: [N,K] @ [K,128] -> g (fp16), + attn
// dots (fp32, computed from fp32 accumulators before rounding).
// ---------------------------------------------------------------------------
template<int K>
__global__ __launch_bounds__(256) void transform_gemm_kernel(
        const float* __restrict__ h, const float* __restrict__ W,
        const float* __restrict__ att_s, const float* __restrict__ att_d,
        __half* __restrict__ g, float* __restrict__ a_src, float* __restrict__ a_dst) {
    __shared__ float Ws[K][64];          // K=128: 32 KB, K=16: 4 KB
    __shared__ float hs[64][K + 4];      // pad +4 floats: break row-bank stack
    int t = threadIdx.x;
    int cq = t & 15;                     // channel quad within half (0..15)
    int nq = t >> 4;                     // node quad (0..15)
    constexpr int KSH = (K == 128) ? 7 : 4;

    for (int item = blockIdx.x; item < NTILES * 2; item += gridDim.x) {
        int tile = item >> 1;
        int coff = (item & 1) << 6;                 // 0 or 64
        int nbase = tile << 6;
        __syncthreads();                            // protect prev iter reads
        // stage W column-half: K x 64
        for (int i = t; i < K * 64; i += 256)
            Ws[i >> 6][i & 63] = W[(size_t)(i >> 6) * HD + coff + (i & 63)];
        // stage 64 h rows (clamped in tail tile)
        for (int i = t; i < (K << 6); i += 256) {
            int r = i >> KSH, k = i & (K - 1);
            int n = nbase + r; if (n >= N_NODES) n = N_NODES - 1;
            hs[r][k] = h[(size_t)n * K + k];
        }
        __syncthreads();

        float acc[4][4] = {{0.f}};
        #pragma unroll 2
        for (int k = 0; k < K; k += 4) {
            float4 w0 = *(const float4*)&Ws[k + 0][cq << 2];
            float4 w1 = *(const float4*)&Ws[k + 1][cq << 2];
            float4 w2 = *(const float4*)&Ws[k + 2][cq << 2];
            float4 w3 = *(const float4*)&Ws[k + 3][cq << 2];
            #pragma unroll
            for (int j = 0; j < 4; ++j) {
                float4 hv = *(const float4*)&hs[(nq << 2) + j][k];
                acc[j][0] += hv.x * w0.x + hv.y * w1.x + hv.z * w2.x + hv.w * w3.x;
                acc[j][1] += hv.x * w0.y + hv.y * w1.y + hv.z * w2.y + hv.w * w3.y;
                acc[j][2] += hv.x * w0.z + hv.y * w1.z + hv.z * w2.z + hv.w * w3.z;
                acc[j][3] += hv.x * w0.w + hv.y * w1.w + hv.z * w2.w + hv.w * w3.w;
            }
        }

        int c0 = coff + (cq << 2);
        float as0 = att_s[c0], as1 = att_s[c0 + 1], as2 = att_s[c0 + 2], as3 = att_s[c0 + 3];
        float ad0 = att_d[c0], ad1 = att_d[c0 + 1], ad2 = att_d[c0 + 2], ad3 = att_d[c0 + 3];
        int head = c0 >> 4;
        #pragma unroll
        for (int j = 0; j < 4; ++j) {
            int n = nbase + (nq << 2) + j;
            float ps = acc[j][0] * as0 + acc[j][1] * as1 + acc[j][2] * as2 + acc[j][3] * as3;
            float pd = acc[j][0] * ad0 + acc[j][1] * ad1 + acc[j][2] * ad2 + acc[j][3] * ad3;
            ps += __shfl_xor(ps, 1); ps += __shfl_xor(ps, 2);
            pd += __shfl_xor(pd, 1); pd += __shfl_xor(pd, 2);
            if (n < N_NODES) {
                union { __half2 h2[2]; uint2 u; } pk;
                pk.h2[0] = __floats2half2_rn(acc[j][0], acc[j][1]);
                pk.h2[1] = __floats2half2_rn(acc[j][2], acc[j][3]);
                *(uint2*)&g[(size_t)n * HD + c0] = pk.u;
                if ((cq & 3) == 0) {
                    a_src[(size_t)n * H_HEADS + head] = ps;
                    a_dst[(size_t)n * H_HEADS + head] = pd;
                }
            }
        }
    }
}

// ---------------------------------------------------------------------------
// CSR build: histogram -> 3-phase multi-block scan -> scatter.
// ---------------------------------------------------------------------------
__global__ __launch_bounds__(256) void hist_kernel(
        const int* __restrict__ ei, int* __restrict__ deg) {
    int e = blockIdx.x * 256 + threadIdx.x;
    if (e < E_EDGES) atomicAdd(&deg[ei[E_EDGES + e]], 1);
}

__global__ __launch_bounds__(SCAN_T) void block_sum_kernel(
        const int* __restrict__ deg, int* __restrict__ bsum) {
    int b = blockIdx.x, t = threadIdx.x;
    int lo = b * SCAN_CH, hi = min(lo + SCAN_CH, N_NODES);
    int s = 0;
    for (int i = lo + t; i < hi; i += SCAN_T) s += deg[i];
    #pragma unroll
    for (int m = 1; m < 64; m <<= 1) s += __shfl_xor(s, m);
    __shared__ int ws[SCAN_T / 64];
    if ((t & 63) == 0) ws[t >> 6] = s;
    __syncthreads();
    if (t == 0) {
        int tot = 0;
        #pragma unroll
        for (int w = 0; w < SCAN_T / 64; ++w) tot += ws[w];
        bsum[b] = tot;
    }
}

__global__ __launch_bounds__(SCAN_BLOCKS) void offset_scan_kernel(
        const int* __restrict__ bsum, int* __restrict__ boff) {
    __shared__ int tmp[SCAN_BLOCKS];
    int t = threadIdx.x;
    int v = bsum[t];
    tmp[t] = v;
    __syncthreads();
    int val = v;
    for (int off = 1; off < SCAN_BLOCKS; off <<= 1) {
        int o = (t >= off) ? tmp[t - off] : 0;
        __syncthreads();
        val += o;
        tmp[t] = val;
        __syncthreads();
    }
    boff[t] = val - v;    // exclusive
}

__global__ __launch_bounds__(SCAN_T) void row_ptr_kernel(
        const int* __restrict__ deg, const int* __restrict__ boff,
        int* __restrict__ row_ptr, int* __restrict__ fill) {
    int b = blockIdx.x, t = threadIdx.x;
    int lo = b * SCAN_CH, hi = min(lo + SCAN_CH, N_NODES);
    __shared__ int tmp[SCAN_T];
    __shared__ int carry;
    if (t == 0) carry = boff[b];
    __syncthreads();
    for (int base = lo; base < hi; base += SCAN_T) {
        int i = base + t;
        int v = (i < hi) ? deg[i] : 0;
        tmp[t] = v;
        __syncthreads();
        int val = v;
        for (int off = 1; off < SCAN_T; off <<= 1) {
            int o = (t >= off) ? tmp[t - off] : 0;
            __syncthreads();
            val += o;
            tmp[t] = val;
            __syncthreads();
        }
        int excl = val - v + carry;
        if (i < hi) { row_ptr[i] = excl; fill[i] = excl; }
        __syncthreads();
        if (t == SCAN_T - 1) carry = carry + val;
        __syncthreads();
    }
    if (b == SCAN_BLOCKS - 1 && t == 0) row_ptr[N_NODES] = carry;  // == E
}

__global__ __launch_bounds__(256) void scatter_kernel(
        const int* __restrict__ ei, int* __restrict__ fill,
        int* __restrict__ col) {
    int e = blockIdx.x * 256 + threadIdx.x;
    if (e < E_EDGES) {
        int d = ei[E_EDGES + e];
        int p = atomicAdd(&fill[d], 1);
        col[p] = ei[e];
    }
}

// ---------------------------------------------------------------------------
// Fused GAT aggregation over CSR: one wave per dst node, no atomics.
// grp = lane>>4 (edge group 0..3), sub = lane&15 (channels 8*sub..8*sub+7,
// head sub>>1). The wave's edge list (<=64 edges, avg 17) is PRELOADED into
// registers with one coalesced load; per-body source ids come from __shfl,
// so all 8 gathers of a 16-edge iteration issue with no VMEM dependence
// (round-7 was MLP-starved on the col->gather chain). deg>64 tail: loop.
// ---------------------------------------------------------------------------
template<bool FUSE>
__global__ __launch_bounds__(256) void gat_aggr_csr_kernel(
        const int* __restrict__ row_ptr, const int* __restrict__ col,
        const float* __restrict__ a_src, const float* __restrict__ a_dst,
        const __half* __restrict__ g, const float* __restrict__ bias,
        float* __restrict__ out,
        const float* __restrict__ Wy1, const float* __restrict__ by1,
        const float* __restrict__ Wy0, const float* __restrict__ by0,
        const float* __restrict__ Wc1, const float* __restrict__ bc1,
        const float* __restrict__ Wc2, const float* __restrict__ bc2) {
    int wv = threadIdx.x >> 6, lane = threadIdx.x & 63;
    int d = blockIdx.x * 4 + wv;
    if (d >= N_NODES) return;
    int grp = lane >> 4;                 // edge group
    int sub = lane & 15;                 // channel slice
    int hh  = sub >> 1;                  // head 0..7
    float ad = a_dst[d * 8 + hh];

    float acc[8] = {0.f, 0.f, 0.f, 0.f, 0.f, 0.f, 0.f, 0.f};
    float den = 0.f;
    int i0 = row_ptr[d], end = row_ptr[d + 1];
    int deg = end - i0;
    int deg64 = min(deg, 64);

    // preload edge sources (one coalesced dword per lane, clamped)
    int colv;
    {
        int ci = i0 + lane;
        ci = (ci < end) ? ci : (end - 1);
        ci = (ci < 0) ? 0 : ci;          // deg==0 safety
        colv = col[ci];
    }

    #define EDGE_BODY(ELOCAL)                                                \
    {                                                                        \
        int el = (ELOCAL);                                                   \
        int s = __shfl(colv, el & 63);                                       \
        float a = a_src[s * 8 + hh] + ad;                                    \
        a = (a > 0.f) ? a : NEG_SLOPE * a;                                   \
        float w = (el < deg64) ? __expf(a) : 0.f;                            \
        uint4 rv = *(const uint4*)(g + (size_t)s * HD + (sub << 3));         \
        float2 f0 = __half22float2(*(__half2*)&rv.x);                        \
        float2 f1 = __half22float2(*(__half2*)&rv.y);                        \
        float2 f2 = __half22float2(*(__half2*)&rv.z);                        \
        float2 f3 = __half22float2(*(__half2*)&rv.w);                        \
        acc[0] += w * f0.x; acc[1] += w * f0.y;                              \
        acc[2] += w * f1.x; acc[3] += w * f1.y;                              \
        acc[4] += w * f2.x; acc[5] += w * f2.y;                              \
        acc[6] += w * f3.x; acc[7] += w * f3.y;                              \
        den += w;                                                            \
    }

    for (int base = 0; base < deg64; base += 16) {
        EDGE_BODY(base + grp);
        EDGE_BODY(base + 4 + grp);
        EDGE_BODY(base + 8 + grp);
        EDGE_BODY(base + 12 + grp);
    }
    #undef EDGE_BODY

    // rare tail: deg > 64 (per-group strided, direct col loads)
    for (int i = i0 + 64 + grp; i < end; i += 4) {
        int s = col[i];
        float a = a_src[s * 8 + hh] + ad;
        a = (a > 0.f) ? a : NEG_SLOPE * a;
        float w = __expf(a);
        uint4 rv = *(const uint4*)(g + (size_t)s * HD + (sub << 3));
        float2 f0 = __half22float2(*(__half2*)&rv.x);
        float2 f1 = __half22float2(*(__half2*)&rv.y);
        float2 f2 = __half22float2(*(__half2*)&rv.z);
        float2 f3 = __half22float2(*(__half2*)&rv.w);
        acc[0] += w * f0.x; acc[1] += w * f0.y;
        acc[2] += w * f1.x; acc[3] += w * f1.y;
        acc[4] += w * f2.x; acc[5] += w * f2.y;
        acc[6] += w * f3.x; acc[7] += w * f3.y;
        den += w;
    }

    // cross-group reduction: sum the 4 edge groups
    #pragma unroll
    for (int k = 0; k < 8; ++k) {
        acc[k] += __shfl_xor(acc[k], 16);
        acc[k] += __shfl_xor(acc[k], 32);
    }
    den += __shfl_xor(den, 16);
    den += __shfl_xor(den, 32);

    // self loop (identical in all lanes of same sub; added ONCE, post-reduce)
    {
        float a = a_src[d * 8 + hh] + ad;
        a = (a > 0.f) ? a : NEG_SLOPE * a;
        float w = __expf(a);
        uint4 rv = *(const uint4*)(g + (size_t)d * HD + (sub << 3));
        float2 f0 = __half22float2(*(__half2*)&rv.x);
        float2 f1 = __half22float2(*(__half2*)&rv.y);
        float2 f2 = __half22float2(*(__half2*)&rv.z);
        float2 f3 = __half22float2(*(__half2*)&rv.w);
        acc[0] += w * f0.x; acc[1] += w * f0.y;
        acc[2] += w * f1.x; acc[3] += w * f1.y;
        acc[4] += w * f2.x; acc[5] += w * f2.y;
        acc[6] += w * f3.x; acc[7] += w * f3.y;
        den += w;
    }

    float inv = 1.f / (den + 1e-16f);
    int c0 = sub << 3;
    float h[8];
    #pragma unroll
    for (int k = 0; k < 8; ++k) h[k] = acc[k] * inv + bias[c0 + k];

    if (!FUSE) {
        // groups 0 and 1 write the two float4 halves (other groups duplicate)
        if (grp == 0) *(float4*)&out[(size_t)d * HD + c0] =
            make_float4(h[0], h[1], h[2], h[3]);
        else if (grp == 1) *(float4*)&out[(size_t)d * HD + c0 + 4] =
            make_float4(h[4], h[5], h[6], h[7]);
    } else {
        // redistribute to (2l, 2l+1)-per-lane layout, then fused heads
        int src = lane >> 2;             // source lane (sub of owner, group 0)
        float t0 = __shfl(h[0], src), t2 = __shfl(h[2], src);
        float t4 = __shfl(h[4], src), t6 = __shfl(h[6], src);
        float t1 = __shfl(h[1], src), t3 = __shfl(h[3], src);
        float t5 = __shfl(h[5], src), t7 = __shfl(h[7], src);
        int m = lane & 3;
        float hA = (m == 0) ? t0 : (m == 1) ? t2 : (m == 2) ? t4 : t6;
        float hB = (m == 0) ? t1 : (m == 1) ? t3 : (m == 2) ? t5 : t7;
        int cc = lane << 1;
        float p = hA * (Wy1[cc] - Wy0[cc]) + hB * (Wy1[cc + 1] - Wy0[cc + 1]);
        #pragma unroll
        for (int mm = 1; mm < 64; mm <<= 1) p += __shfl_xor(p, mm);
        float acc2 = 0.f;
        #pragma unroll
        for (int j = 0; j < D_DIM; ++j) {
            float q = hA * Wc1[cc * D_DIM + j] + hB * Wc1[(cc + 1) * D_DIM + j];
            #pragma unroll
            for (int mm = 1; mm < 64; mm <<= 1) q += __shfl_xor(q, mm);
            float z = q + bc1[j];
            z = (z > 0.f) ? z : 0.f;
            acc2 += z * Wc2[j];
        }
        if (lane == 0) {
            out[d] = p + by1[0] - by0[0];
            out[N_NODES + d] = 1.f / (1.f + __expf(-(acc2 + bc2[0])));
        }
    }
}

// ---------------------------------------------------------------------------
extern "C" void kernel_launch(void* const* d_in, const int* in_sizes, int n_in,
                              void* d_out, int out_size, void* d_ws, size_t ws_size,
                              hipStream_t stream) {
    const float* x     = (const float*)d_in[0];
    const int*   ei    = (const int*)  d_in[1];
    const float* W_emb = (const float*)d_in[2];
    const float* b_emb = (const float*)d_in[3];
    const float* W0    = (const float*)d_in[4];
    const float* as0   = (const float*)d_in[5];
    const float* ad0   = (const float*)d_in[6];
    const float* b0    = (const float*)d_in[7];
    const float* W1    = (const float*)d_in[8];
    const float* as1   = (const float*)d_in[9];
    const float* ad1   = (const float*)d_in[10];
    const float* b1    = (const float*)d_in[11];
    const float* Wy1   = (const float*)d_in[12];
    const float* by1   = (const float*)d_in[13];
    const float* Wy0   = (const float*)d_in[14];
    const float* by0   = (const float*)d_in[15];
    const float* Wc1   = (const float*)d_in[16];
    const float* bc1   = (const float*)d_in[17];
    const float* Wc2   = (const float*)d_in[18];
    const float* bc2   = (const float*)d_in[19];
    float* out = (float*)d_out;

    float* ws    = (float*)d_ws;
    __half* gH   = (__half*)ws;                          // N*128 halves (25.6MB)
    float* bufH  = (float*)(ws + (size_t)N_NODES * HD / 2 + 64);  // N*128 f32
    float* h0    = bufH + (size_t)N_NODES * HD;          // N*16
    float* a_s   = h0   + (size_t)N_NODES * D_DIM;       // N*8
    float* a_d   = a_s  + (size_t)N_NODES * H_HEADS;     // N*8
    int*   deg     = (int*)(a_d + (size_t)N_NODES * H_HEADS);  // N
    int*   fill    = deg + N_NODES;                            // N
    int*   row_ptr = fill + N_NODES;                           // N+1
    int*   bsum    = row_ptr + (N_NODES + 1);                  // 256
    int*   boff    = bsum + SCAN_BLOCKS;                       // 256
    int*   col     = boff + SCAN_BLOCKS;                       // E

    int edgeBlocks = (E_EDGES + 255) / 256;
    int aggrBlocks = (N_NODES + 3) / 4;

    // ----- CSR build (once; reused by both layers) -----
    hipMemsetAsync(deg, 0, (size_t)N_NODES * sizeof(int), stream);
    hipLaunchKernelGGL(hist_kernel, dim3(edgeBlocks), dim3(256), 0, stream, ei, deg);
    hipLaunchKernelGGL(block_sum_kernel, dim3(SCAN_BLOCKS), dim3(SCAN_T), 0, stream,
                       deg, bsum);
    hipLaunchKernelGGL(offset_scan_kernel, dim3(1), dim3(SCAN_BLOCKS), 0, stream,
                       bsum, boff);
    hipLaunchKernelGGL(row_ptr_kernel, dim3(SCAN_BLOCKS), dim3(SCAN_T), 0, stream,
                       deg, boff, row_ptr, fill);
    hipLaunchKernelGGL(scatter_kernel, dim3(edgeBlocks), dim3(256), 0, stream,
                       ei, fill, col);

    // ----- Embedding -----
    hipLaunchKernelGGL(embed_kernel, dim3(512), dim3(256), 0, stream,
                       x, W_emb, b_emb, h0);

    // ----- GAT layer 0 (K = 16) -----
    hipLaunchKernelGGL(transform_gemm_kernel<16>, dim3(2048), dim3(256), 0, stream,
                       h0, W0, as0, ad0, gH, a_s, a_d);
    hipLaunchKernelGGL(gat_aggr_csr_kernel<false>, dim3(aggrBlocks), dim3(256), 0, stream,
                       row_ptr, col, a_s, a_d, gH, b0, bufH,
                       (const float*)nullptr, (const float*)nullptr,
                       (const float*)nullptr, (const float*)nullptr,
                       (const float*)nullptr, (const float*)nullptr,
                       (const float*)nullptr, (const float*)nullptr);

    // ----- GAT layer 1 (K = 128) + fused heads -----
    hipLaunchKernelGGL(transform_gemm_kernel<128>, dim3(1024), dim3(256), 0, stream,
                       bufH, W1, as1, ad1, gH, a_s, a_d);
    hipLaunchKernelGGL(gat_aggr_csr_kernel<true>, dim3(aggrBlocks), dim3(256), 0, stream,
                       row_ptr, col, a_s, a_d, gH, b1, out,
                       Wy1, by1, Wy0, by0, Wc1, bc1, Wc2, bc2);
}

// Round 9
// 571.151 us; speedup vs baseline: 1.0180x; 1.0040x over previous
//
#include <hip/hip_runtime.h>
#include <hip/hip_fp16.h>
#include <math.h>

#define N_NODES 100000
#define E_EDGES 1600000
#define F_IN 128
#define D_DIM 16
#define H_HEADS 8
#define HD 128
#define NEG_SLOPE 0.2f

#define SCAN_BLOCKS 256
#define SCAN_T 256
#define SCAN_CH ((N_NODES + SCAN_BLOCKS - 1) / SCAN_BLOCKS)   // 391

#define NTILES ((N_NODES + 63) / 64)        // 1563 node-tiles of 64

// ---------------------------------------------------------------------------
// Embedding: h0[n, 0..15] = x[n, :] @ W_emb + b_emb
// ---------------------------------------------------------------------------
__global__ __launch_bounds__(256) void embed_kernel(
        const float* __restrict__ x, const float* __restrict__ W,
        const float* __restrict__ b, float* __restrict__ h0) {
    __shared__ float Ws[F_IN * D_DIM];   // 8 KB
    __shared__ float bs[D_DIM];
    __shared__ float xs[16][F_IN + 1];
    int t = threadIdx.x;
    for (int i = t; i < F_IN * D_DIM; i += 256) Ws[i] = W[i];
    if (t < D_DIM) bs[t] = b[t];
    __syncthreads();
    for (int base = blockIdx.x * 16; base < N_NODES; base += gridDim.x * 16) {
        int cnt = min(16, N_NODES - base);
        __syncthreads();
        for (int i = t; i < cnt * F_IN; i += 256) {
            int nn = i >> 7, k = i & 127;
            xs[nn][k] = x[(size_t)(base + nn) * F_IN + k];
        }
        __syncthreads();
        int nn = t >> 4, c = t & 15;
        if (nn < cnt) {
            float a0 = 0.f, a1 = 0.f, a2 = 0.f, a3 = 0.f;
            #pragma unroll
            for (int k = 0; k < F_IN; k += 4) {
                a0 += xs[nn][k + 0] * Ws[(k + 0) * D_DIM + c];
                a1 += xs[nn][k + 1] * Ws[(k + 1) * D_DIM + c];
                a2 += xs[nn][k + 2] * Ws[(k + 2) * D_DIM + c];
                a3 += xs[nn][k + 3] * Ws[(k + 3) * D_DIM + c];
            }
            h0[(size_t)(base + nn) * D_DIM + c] = (a0 + a1) + (a2 + a3) + bs[c];
        }
    }
}

// ---------------------------------------------------------------------------
// Node transform as register-tiled GEMM: [N,K] @ [K,128] -> g (fp16), + attn
// dots (fp32, computed from fp32 accumulators before rounding).
// ---------------------------------------------------------------------------
template<int K>
__global__ __launch_bounds__(256) void transform_gemm_kernel(
        const float* __restrict__ h, const float* __restrict__ W,
        const float* __restrict__ att_s, const float* __restrict__ att_d,
        __half* __restrict__ g, float* __restrict__ a_src, float* __restrict__ a_dst) {
    __shared__ float Ws[K][64];          // K=128: 32 KB, K=16: 4 KB
    __shared__ float hs[64][K + 4];      // pad +4 floats: break row-bank stack
    int t = threadIdx.x;
    int cq = t & 15;                     // channel quad within half (0..15)
    int nq = t >> 4;                     // node quad (0..15)
    constexpr int KSH = (K == 128) ? 7 : 4;

    for (int item = blockIdx.x; item < NTILES * 2; item += gridDim.x) {
        int tile = item >> 1;
        int coff = (item & 1) << 6;                 // 0 or 64
        int nbase = tile << 6;
        __syncthreads();                            // protect prev iter reads
        // stage W column-half: K x 64
        for (int i = t; i < K * 64; i += 256)
            Ws[i >> 6][i & 63] = W[(size_t)(i >> 6) * HD + coff + (i & 63)];
        // stage 64 h rows (clamped in tail tile)
        for (int i = t; i < (K << 6); i += 256) {
            int r = i >> KSH, k = i & (K - 1);
            int n = nbase + r; if (n >= N_NODES) n = N_NODES - 1;
            hs[r][k] = h[(size_t)n * K + k];
        }
        __syncthreads();

        float acc[4][4] = {{0.f}};
        #pragma unroll 2
        for (int k = 0; k < K; k += 4) {
            float4 w0 = *(const float4*)&Ws[k + 0][cq << 2];
            float4 w1 = *(const float4*)&Ws[k + 1][cq << 2];
            float4 w2 = *(const float4*)&Ws[k + 2][cq << 2];
            float4 w3 = *(const float4*)&Ws[k + 3][cq << 2];
            #pragma unroll
            for (int j = 0; j < 4; ++j) {
                float4 hv = *(const float4*)&hs[(nq << 2) + j][k];
                acc[j][0] += hv.x * w0.x + hv.y * w1.x + hv.z * w2.x + hv.w * w3.x;
                acc[j][1] += hv.x * w0.y + hv.y * w1.y + hv.z * w2.y + hv.w * w3.y;
                acc[j][2] += hv.x * w0.z + hv.y * w1.z + hv.z * w2.z + hv.w * w3.z;
                acc[j][3] += hv.x * w0.w + hv.y * w1.w + hv.z * w2.w + hv.w * w3.w;
            }
        }

        int c0 = coff + (cq << 2);
        float as0 = att_s[c0], as1 = att_s[c0 + 1], as2 = att_s[c0 + 2], as3 = att_s[c0 + 3];
        float ad0 = att_d[c0], ad1 = att_d[c0 + 1], ad2 = att_d[c0 + 2], ad3 = att_d[c0 + 3];
        int head = c0 >> 4;
        #pragma unroll
        for (int j = 0; j < 4; ++j) {
            int n = nbase + (nq << 2) + j;
            float ps = acc[j][0] * as0 + acc[j][1] * as1 + acc[j][2] * as2 + acc[j][3] * as3;
            float pd = acc[j][0] * ad0 + acc[j][1] * ad1 + acc[j][2] * ad2 + acc[j][3] * ad3;
            ps += __shfl_xor(ps, 1); ps += __shfl_xor(ps, 2);
            pd += __shfl_xor(pd, 1); pd += __shfl_xor(pd, 2);
            if (n < N_NODES) {
                union { __half2 h2[2]; uint2 u; } pk;
                pk.h2[0] = __floats2half2_rn(acc[j][0], acc[j][1]);
                pk.h2[1] = __floats2half2_rn(acc[j][2], acc[j][3]);
                *(uint2*)&g[(size_t)n * HD + c0] = pk.u;
                if ((cq & 3) == 0) {
                    a_src[(size_t)n * H_HEADS + head] = ps;
                    a_dst[(size_t)n * H_HEADS + head] = pd;
                }
            }
        }
    }
}

// ---------------------------------------------------------------------------
// CSR build: histogram -> 3-phase multi-block scan -> scatter.
// ---------------------------------------------------------------------------
__global__ __launch_bounds__(256) void hist_kernel(
        const int* __restrict__ ei, int* __restrict__ deg) {
    int e = blockIdx.x * 256 + threadIdx.x;
    if (e < E_EDGES) atomicAdd(&deg[ei[E_EDGES + e]], 1);
}

__global__ __launch_bounds__(SCAN_T) void block_sum_kernel(
        const int* __restrict__ deg, int* __restrict__ bsum) {
    int b = blockIdx.x, t = threadIdx.x;
    int lo = b * SCAN_CH, hi = min(lo + SCAN_CH, N_NODES);
    int s = 0;
    for (int i = lo + t; i < hi; i += SCAN_T) s += deg[i];
    #pragma unroll
    for (int m = 1; m < 64; m <<= 1) s += __shfl_xor(s, m);
    __shared__ int ws[SCAN_T / 64];
    if ((t & 63) == 0) ws[t >> 6] = s;
    __syncthreads();
    if (t == 0) {
        int tot = 0;
        #pragma unroll
        for (int w = 0; w < SCAN_T / 64; ++w) tot += ws[w];
        bsum[b] = tot;
    }
}

__global__ __launch_bounds__(SCAN_BLOCKS) void offset_scan_kernel(
        const int* __restrict__ bsum, int* __restrict__ boff) {
    __shared__ int tmp[SCAN_BLOCKS];
    int t = threadIdx.x;
    int v = bsum[t];
    tmp[t] = v;
    __syncthreads();
    int val = v;
    for (int off = 1; off < SCAN_BLOCKS; off <<= 1) {
        int o = (t >= off) ? tmp[t - off] : 0;
        __syncthreads();
        val += o;
        tmp[t] = val;
        __syncthreads();
    }
    boff[t] = val - v;    // exclusive
}

__global__ __launch_bounds__(SCAN_T) void row_ptr_kernel(
        const int* __restrict__ deg, const int* __restrict__ boff,
        int* __restrict__ row_ptr, int* __restrict__ fill) {
    int b = blockIdx.x, t = threadIdx.x;
    int lo = b * SCAN_CH, hi = min(lo + SCAN_CH, N_NODES);
    __shared__ int tmp[SCAN_T];
    __shared__ int carry;
    if (t == 0) carry = boff[b];
    __syncthreads();
    for (int base = lo; base < hi; base += SCAN_T) {
        int i = base + t;
        int v = (i < hi) ? deg[i] : 0;
        tmp[t] = v;
        __syncthreads();
        int val = v;
        for (int off = 1; off < SCAN_T; off <<= 1) {
            int o = (t >= off) ? tmp[t - off] : 0;
            __syncthreads();
            val += o;
            tmp[t] = val;
            __syncthreads();
        }
        int excl = val - v + carry;
        if (i < hi) { row_ptr[i] = excl; fill[i] = excl; }
        __syncthreads();
        if (t == SCAN_T - 1) carry = carry + val;
        __syncthreads();
    }
    if (b == SCAN_BLOCKS - 1 && t == 0) row_ptr[N_NODES] = carry;  // == E
}

__global__ __launch_bounds__(256) void scatter_kernel(
        const int* __restrict__ ei, int* __restrict__ fill,
        int* __restrict__ col) {
    int e = blockIdx.x * 256 + threadIdx.x;
    if (e < E_EDGES) {
        int d = ei[E_EDGES + e];
        int p = atomicAdd(&fill[d], 1);
        col[p] = ei[e];
    }
}

// ---------------------------------------------------------------------------
// Fused GAT aggregation over CSR: one wave per dst node, no atomics.
// grp = lane>>4 (edge group 0..3), sub = lane&15 (channels 8*sub..8*sub+7,
// head sub>>1). Edge list (<=64) preloaded to registers (shfl for src ids).
// NEW vs round 8: (1) packed-fp16 accumulation (__hfma2, 4 pk_fma/edge-lane
// replaces 8 cvt + 8 fma); (2) explicit A/B double-buffer: body i+1's
// col-shfl + a_src + uint4 loads issue BEFORE body i's math, so each wave
// keeps ~16 edges (4 KB) of gathers in flight across the compute phase.
// All prefetch guards are wave-uniform (deg64 is per-dst).
// ---------------------------------------------------------------------------
template<bool FUSE>
__global__ __launch_bounds__(256) void gat_aggr_csr_kernel(
        const int* __restrict__ row_ptr, const int* __restrict__ col,
        const float* __restrict__ a_src, const float* __restrict__ a_dst,
        const __half* __restrict__ g, const float* __restrict__ bias,
        float* __restrict__ out,
        const float* __restrict__ Wy1, const float* __restrict__ by1,
        const float* __restrict__ Wy0, const float* __restrict__ by0,
        const float* __restrict__ Wc1, const float* __restrict__ bc1,
        const float* __restrict__ Wc2, const float* __restrict__ bc2) {
    int wv = threadIdx.x >> 6, lane = threadIdx.x & 63;
    int d = blockIdx.x * 4 + wv;
    if (d >= N_NODES) return;
    int grp = lane >> 4;                 // edge group
    int sub = lane & 15;                 // channel slice
    int hh  = sub >> 1;                  // head 0..7
    float ad = a_dst[d * 8 + hh];

    __half2 acc2[4];
    acc2[0] = __float2half2_rn(0.f); acc2[1] = __float2half2_rn(0.f);
    acc2[2] = __float2half2_rn(0.f); acc2[3] = __float2half2_rn(0.f);
    float den = 0.f;
    int i0 = row_ptr[d], end = row_ptr[d + 1];
    int deg = end - i0;
    int deg64 = min(deg, 64);

    // preload edge sources (one coalesced dword per lane, clamped)
    int colv;
    {
        int ci = i0 + lane;
        ci = (ci < end) ? ci : (end - 1);
        ci = (ci < 0) ? 0 : ci;          // deg==0 safety
        colv = col[ci];
    }

    // named A/B register sets (no runtime indexing -> no scratch)
    int sA0, sA1, sA2, sA3, sB0, sB1, sB2, sB3;
    float vA0, vA1, vA2, vA3, vB0, vB1, vB2, vB3;
    uint4 rA0, rA1, rA2, rA3, rB0, rB1, rB2, rB3;

    #define ISSUE(BASE, S0, S1, S2, S3, V0, V1, V2, V3, R0, R1, R2, R3)      \
    {                                                                        \
        S0 = __shfl(colv, ((BASE) +  0 + grp) & 63);                         \
        S1 = __shfl(colv, ((BASE) +  4 + grp) & 63);                         \
        S2 = __shfl(colv, ((BASE) +  8 + grp) & 63);                         \
        S3 = __shfl(colv, ((BASE) + 12 + grp) & 63);                         \
        V0 = a_src[S0 * 8 + hh];  V1 = a_src[S1 * 8 + hh];                   \
        V2 = a_src[S2 * 8 + hh];  V3 = a_src[S3 * 8 + hh];                   \
        R0 = *(const uint4*)(g + (size_t)S0 * HD + (sub << 3));              \
        R1 = *(const uint4*)(g + (size_t)S1 * HD + (sub << 3));              \
        R2 = *(const uint4*)(g + (size_t)S2 * HD + (sub << 3));              \
        R3 = *(const uint4*)(g + (size_t)S3 * HD + (sub << 3));              \
    }

    #define CONSUME1(EL, V, R)                                               \
    {                                                                        \
        float a = (V) + ad;                                                  \
        a = fmaxf(a, NEG_SLOPE * a);                                         \
        float w = ((EL) < deg64) ? __expf(a) : 0.f;                          \
        den += w;                                                            \
        __half2 w2 = __float2half2_rn(w);                                    \
        const __half2* p = (const __half2*)&(R);                             \
        acc2[0] = __hfma2(w2, p[0], acc2[0]);                                \
        acc2[1] = __hfma2(w2, p[1], acc2[1]);                                \
        acc2[2] = __hfma2(w2, p[2], acc2[2]);                                \
        acc2[3] = __hfma2(w2, p[3], acc2[3]);                                \
    }

    #define CONSUME(BASE, V0, V1, V2, V3, R0, R1, R2, R3)                    \
    {                                                                        \
        CONSUME1((BASE) +  0 + grp, V0, R0);                                 \
        CONSUME1((BASE) +  4 + grp, V1, R1);                                 \
        CONSUME1((BASE) +  8 + grp, V2, R2);                                 \
        CONSUME1((BASE) + 12 + grp, V3, R3);                                 \
    }

    if (deg64 > 0) {
        ISSUE(0, sA0, sA1, sA2, sA3, vA0, vA1, vA2, vA3, rA0, rA1, rA2, rA3);
        for (int base = 0; base < deg64; base += 32) {
            if (base + 16 < deg64)
                ISSUE(base + 16, sB0, sB1, sB2, sB3, vB0, vB1, vB2, vB3,
                      rB0, rB1, rB2, rB3);
            CONSUME(base, vA0, vA1, vA2, vA3, rA0, rA1, rA2, rA3);
            if (base + 32 < deg64)
                ISSUE(base + 32, sA0, sA1, sA2, sA3, vA0, vA1, vA2, vA3,
                      rA0, rA1, rA2, rA3);
            if (base + 16 < deg64)
                CONSUME(base + 16, vB0, vB1, vB2, vB3, rB0, rB1, rB2, rB3);
        }
    }
    #undef ISSUE
    #undef CONSUME
    #undef CONSUME1

    // convert packed accumulators to f32
    float acc[8];
    {
        float2 f0 = __half22float2(acc2[0]);
        float2 f1 = __half22float2(acc2[1]);
        float2 f2 = __half22float2(acc2[2]);
        float2 f3 = __half22float2(acc2[3]);
        acc[0] = f0.x; acc[1] = f0.y; acc[2] = f1.x; acc[3] = f1.y;
        acc[4] = f2.x; acc[5] = f2.y; acc[6] = f3.x; acc[7] = f3.y;
    }

    // rare tail: deg > 64 (per-group strided, direct col loads, f32 math)
    for (int i = i0 + 64 + grp; i < end; i += 4) {
        int s = col[i];
        float a = a_src[s * 8 + hh] + ad;
        a = fmaxf(a, NEG_SLOPE * a);
        float w = __expf(a);
        uint4 rv = *(const uint4*)(g + (size_t)s * HD + (sub << 3));
        float2 f0 = __half22float2(*(__half2*)&rv.x);
        float2 f1 = __half22float2(*(__half2*)&rv.y);
        float2 f2 = __half22float2(*(__half2*)&rv.z);
        float2 f3 = __half22float2(*(__half2*)&rv.w);
        acc[0] += w * f0.x; acc[1] += w * f0.y;
        acc[2] += w * f1.x; acc[3] += w * f1.y;
        acc[4] += w * f2.x; acc[5] += w * f2.y;
        acc[6] += w * f3.x; acc[7] += w * f3.y;
        den += w;
    }

    // cross-group reduction: sum the 4 edge groups (f32)
    #pragma unroll
    for (int k = 0; k < 8; ++k) {
        acc[k] += __shfl_xor(acc[k], 16);
        acc[k] += __shfl_xor(acc[k], 32);
    }
    den += __shfl_xor(den, 16);
    den += __shfl_xor(den, 32);

    // self loop (identical in all lanes of same sub; added ONCE, post-reduce)
    {
        float a = a_src[d * 8 + hh] + ad;
        a = fmaxf(a, NEG_SLOPE * a);
        float w = __expf(a);
        uint4 rv = *(const uint4*)(g + (size_t)d * HD + (sub << 3));
        float2 f0 = __half22float2(*(__half2*)&rv.x);
        float2 f1 = __half22float2(*(__half2*)&rv.y);
        float2 f2 = __half22float2(*(__half2*)&rv.z);
        float2 f3 = __half22float2(*(__half2*)&rv.w);
        acc[0] += w * f0.x; acc[1] += w * f0.y;
        acc[2] += w * f1.x; acc[3] += w * f1.y;
        acc[4] += w * f2.x; acc[5] += w * f2.y;
        acc[6] += w * f3.x; acc[7] += w * f3.y;
        den += w;
    }

    float inv = 1.f / (den + 1e-16f);
    int c0 = sub << 3;
    float h[8];
    #pragma unroll
    for (int k = 0; k < 8; ++k) h[k] = acc[k] * inv + bias[c0 + k];

    if (!FUSE) {
        // groups 0 and 1 write the two float4 halves (other groups duplicate)
        if (grp == 0) *(float4*)&out[(size_t)d * HD + c0] =
            make_float4(h[0], h[1], h[2], h[3]);
        else if (grp == 1) *(float4*)&out[(size_t)d * HD + c0 + 4] =
            make_float4(h[4], h[5], h[6], h[7]);
    } else {
        // redistribute to (2l, 2l+1)-per-lane layout, then fused heads
        int src = lane >> 2;             // source lane (sub of owner, group 0)
        float t0 = __shfl(h[0], src), t2 = __shfl(h[2], src);
        float t4 = __shfl(h[4], src), t6 = __shfl(h[6], src);
        float t1 = __shfl(h[1], src), t3 = __shfl(h[3], src);
        float t5 = __shfl(h[5], src), t7 = __shfl(h[7], src);
        int m = lane & 3;
        float hA = (m == 0) ? t0 : (m == 1) ? t2 : (m == 2) ? t4 : t6;
        float hB = (m == 0) ? t1 : (m == 1) ? t3 : (m == 2) ? t5 : t7;
        int cc = lane << 1;
        float p = hA * (Wy1[cc] - Wy0[cc]) + hB * (Wy1[cc + 1] - Wy0[cc + 1]);
        #pragma unroll
        for (int mm = 1; mm < 64; mm <<= 1) p += __shfl_xor(p, mm);
        float acc2f = 0.f;
        #pragma unroll
        for (int j = 0; j < D_DIM; ++j) {
            float q = hA * Wc1[cc * D_DIM + j] + hB * Wc1[(cc + 1) * D_DIM + j];
            #pragma unroll
            for (int mm = 1; mm < 64; mm <<= 1) q += __shfl_xor(q, mm);
            float z = q + bc1[j];
            z = (z > 0.f) ? z : 0.f;
            acc2f += z * Wc2[j];
        }
        if (lane == 0) {
            out[d] = p + by1[0] - by0[0];
            out[N_NODES + d] = 1.f / (1.f + __expf(-(acc2f + bc2[0])));
        }
    }
}

// ---------------------------------------------------------------------------
extern "C" void kernel_launch(void* const* d_in, const int* in_sizes, int n_in,
                              void* d_out, int out_size, void* d_ws, size_t ws_size,
                              hipStream_t stream) {
    const float* x     = (const float*)d_in[0];
    const int*   ei    = (const int*)  d_in[1];
    const float* W_emb = (const float*)d_in[2];
    const float* b_emb = (const float*)d_in[3];
    const float* W0    = (const float*)d_in[4];
    const float* as0   = (const float*)d_in[5];
    const float* ad0   = (const float*)d_in[6];
    const float* b0    = (const float*)d_in[7];
    const float* W1    = (const float*)d_in[8];
    const float* as1   = (const float*)d_in[9];
    const float* ad1   = (const float*)d_in[10];
    const float* b1    = (const float*)d_in[11];
    const float* Wy1   = (const float*)d_in[12];
    const float* by1   = (const float*)d_in[13];
    const float* Wy0   = (const float*)d_in[14];
    const float* by0   = (const float*)d_in[15];
    const float* Wc1   = (const float*)d_in[16];
    const float* bc1   = (const float*)d_in[17];
    const float* Wc2   = (const float*)d_in[18];
    const float* bc2   = (const float*)d_in[19];
    float* out = (float*)d_out;

    float* ws    = (float*)d_ws;
    __half* gH   = (__half*)ws;                          // N*128 halves (25.6MB)
    float* bufH  = (float*)(ws + (size_t)N_NODES * HD / 2 + 64);  // N*128 f32
    float* h0    = bufH + (size_t)N_NODES * HD;          // N*16
    float* a_s   = h0   + (size_t)N_NODES * D_DIM;       // N*8
    float* a_d   = a_s  + (size_t)N_NODES * H_HEADS;     // N*8
    int*   deg     = (int*)(a_d + (size_t)N_NODES * H_HEADS);  // N
    int*   fill    = deg + N_NODES;                            // N
    int*   row_ptr = fill + N_NODES;                           // N+1
    int*   bsum    = row_ptr + (N_NODES + 1);                  // 256
    int*   boff    = bsum + SCAN_BLOCKS;                       // 256
    int*   col     = boff + SCAN_BLOCKS;                       // E

    int edgeBlocks = (E_EDGES + 255) / 256;
    int aggrBlocks = (N_NODES + 3) / 4;

    // ----- CSR build (once; reused by both layers) -----
    hipMemsetAsync(deg, 0, (size_t)N_NODES * sizeof(int), stream);
    hipLaunchKernelGGL(hist_kernel, dim3(edgeBlocks), dim3(256), 0, stream, ei, deg);
    hipLaunchKernelGGL(block_sum_kernel, dim3(SCAN_BLOCKS), dim3(SCAN_T), 0, stream,
                       deg, bsum);
    hipLaunchKernelGGL(offset_scan_kernel, dim3(1), dim3(SCAN_BLOCKS), 0, stream,
                       bsum, boff);
    hipLaunchKernelGGL(row_ptr_kernel, dim3(SCAN_BLOCKS), dim3(SCAN_T), 0, stream,
                       deg, boff, row_ptr, fill);
    hipLaunchKernelGGL(scatter_kernel, dim3(edgeBlocks), dim3(256), 0, stream,
                       ei, fill, col);

    // ----- Embedding -----
    hipLaunchKernelGGL(embed_kernel, dim3(512), dim3(256), 0, stream,
                       x, W_emb, b_emb, h0);

    // ----- GAT layer 0 (K = 16) -----
    hipLaunchKernelGGL(transform_gemm_kernel<16>, dim3(2048), dim3(256), 0, stream,
                       h0, W0, as0, ad0, gH, a_s, a_d);
    hipLaunchKernelGGL(gat_aggr_csr_kernel<false>, dim3(aggrBlocks), dim3(256), 0, stream,
                       row_ptr, col, a_s, a_d, gH, b0, bufH,
                       (const float*)nullptr, (const float*)nullptr,
                       (const float*)nullptr, (const float*)nullptr,
                       (const float*)nullptr, (const float*)nullptr,
                       (const float*)nullptr, (const float*)nullptr);

    // ----- GAT layer 1 (K = 128) + fused heads -----
    hipLaunchKernelGGL(transform_gemm_kernel<128>, dim3(1024), dim3(256), 0, stream,
                       bufH, W1, as1, ad1, gH, a_s, a_d);
    hipLaunchKernelGGL(gat_aggr_csr_kernel<true>, dim3(aggrBlocks), dim3(256), 0, stream,
                       row_ptr, col, a_s, a_d, gH, b1, out,
                       Wy1, by1, Wy0, by0, Wc1, bc1, Wc2, bc2);
}

// Round 10
// 550.607 us; speedup vs baseline: 1.0560x; 1.0373x over previous
//
#include <hip/hip_runtime.h>
#include <hip/hip_fp16.h>
#include <math.h>

#define N_NODES 100000
#define E_EDGES 1600000
#define F_IN 128
#define D_DIM 16
#define H_HEADS 8
#define HD 128
#define NEG_SLOPE 0.2f

#define SCAN_BLOCKS 256
#define SCAN_T 256
#define SCAN_CH ((N_NODES + SCAN_BLOCKS - 1) / SCAN_BLOCKS)   // 391

#define NTILES ((N_NODES + 63) / 64)        // 1563 node-tiles of 64

// ---------------------------------------------------------------------------
// Embedding: h0[n, 0..15] = x[n, :] @ W_emb + b_emb
// ---------------------------------------------------------------------------
__global__ __launch_bounds__(256) void embed_kernel(
        const float* __restrict__ x, const float* __restrict__ W,
        const float* __restrict__ b, float* __restrict__ h0) {
    __shared__ float Ws[F_IN * D_DIM];   // 8 KB
    __shared__ float bs[D_DIM];
    __shared__ float xs[16][F_IN + 1];
    int t = threadIdx.x;
    for (int i = t; i < F_IN * D_DIM; i += 256) Ws[i] = W[i];
    if (t < D_DIM) bs[t] = b[t];
    __syncthreads();
    for (int base = blockIdx.x * 16; base < N_NODES; base += gridDim.x * 16) {
        int cnt = min(16, N_NODES - base);
        __syncthreads();
        for (int i = t; i < cnt * F_IN; i += 256) {
            int nn = i >> 7, k = i & 127;
            xs[nn][k] = x[(size_t)(base + nn) * F_IN + k];
        }
        __syncthreads();
        int nn = t >> 4, c = t & 15;
        if (nn < cnt) {
            float a0 = 0.f, a1 = 0.f, a2 = 0.f, a3 = 0.f;
            #pragma unroll
            for (int k = 0; k < F_IN; k += 4) {
                a0 += xs[nn][k + 0] * Ws[(k + 0) * D_DIM + c];
                a1 += xs[nn][k + 1] * Ws[(k + 1) * D_DIM + c];
                a2 += xs[nn][k + 2] * Ws[(k + 2) * D_DIM + c];
                a3 += xs[nn][k + 3] * Ws[(k + 3) * D_DIM + c];
            }
            h0[(size_t)(base + nn) * D_DIM + c] = (a0 + a1) + (a2 + a3) + bs[c];
        }
    }
}

// ---------------------------------------------------------------------------
// Node transform as register-tiled GEMM: [N,K] @ [K,128] -> g (fp16), + attn
// dots (fp32, computed from fp32 accumulators before rounding).
// ---------------------------------------------------------------------------
template<int K>
__global__ __launch_bounds__(256) void transform_gemm_kernel(
        const float* __restrict__ h, const float* __restrict__ W,
        const float* __restrict__ att_s, const float* __restrict__ att_d,
        __half* __restrict__ g, float* __restrict__ a_src, float* __restrict__ a_dst) {
    __shared__ float Ws[K][64];          // K=128: 32 KB, K=16: 4 KB
    __shared__ float hs[64][K + 4];      // pad +4 floats: break row-bank stack
    int t = threadIdx.x;
    int cq = t & 15;                     // channel quad within half (0..15)
    int nq = t >> 4;                     // node quad (0..15)
    constexpr int KSH = (K == 128) ? 7 : 4;

    for (int item = blockIdx.x; item < NTILES * 2; item += gridDim.x) {
        int tile = item >> 1;
        int coff = (item & 1) << 6;                 // 0 or 64
        int nbase = tile << 6;
        __syncthreads();                            // protect prev iter reads
        // stage W column-half: K x 64
        for (int i = t; i < K * 64; i += 256)
            Ws[i >> 6][i & 63] = W[(size_t)(i >> 6) * HD + coff + (i & 63)];
        // stage 64 h rows (clamped in tail tile)
        for (int i = t; i < (K << 6); i += 256) {
            int r = i >> KSH, k = i & (K - 1);
            int n = nbase + r; if (n >= N_NODES) n = N_NODES - 1;
            hs[r][k] = h[(size_t)n * K + k];
        }
        __syncthreads();

        float acc[4][4] = {{0.f}};
        #pragma unroll 2
        for (int k = 0; k < K; k += 4) {
            float4 w0 = *(const float4*)&Ws[k + 0][cq << 2];
            float4 w1 = *(const float4*)&Ws[k + 1][cq << 2];
            float4 w2 = *(const float4*)&Ws[k + 2][cq << 2];
            float4 w3 = *(const float4*)&Ws[k + 3][cq << 2];
            #pragma unroll
            for (int j = 0; j < 4; ++j) {
                float4 hv = *(const float4*)&hs[(nq << 2) + j][k];
                acc[j][0] += hv.x * w0.x + hv.y * w1.x + hv.z * w2.x + hv.w * w3.x;
                acc[j][1] += hv.x * w0.y + hv.y * w1.y + hv.z * w2.y + hv.w * w3.y;
                acc[j][2] += hv.x * w0.z + hv.y * w1.z + hv.z * w2.z + hv.w * w3.z;
                acc[j][3] += hv.x * w0.w + hv.y * w1.w + hv.z * w2.w + hv.w * w3.w;
            }
        }

        int c0 = coff + (cq << 2);
        float as0 = att_s[c0], as1 = att_s[c0 + 1], as2 = att_s[c0 + 2], as3 = att_s[c0 + 3];
        float ad0 = att_d[c0], ad1 = att_d[c0 + 1], ad2 = att_d[c0 + 2], ad3 = att_d[c0 + 3];
        int head = c0 >> 4;
        #pragma unroll
        for (int j = 0; j < 4; ++j) {
            int n = nbase + (nq << 2) + j;
            float ps = acc[j][0] * as0 + acc[j][1] * as1 + acc[j][2] * as2 + acc[j][3] * as3;
            float pd = acc[j][0] * ad0 + acc[j][1] * ad1 + acc[j][2] * ad2 + acc[j][3] * ad3;
            ps += __shfl_xor(ps, 1); ps += __shfl_xor(ps, 2);
            pd += __shfl_xor(pd, 1); pd += __shfl_xor(pd, 2);
            if (n < N_NODES) {
                union { __half2 h2[2]; uint2 u; } pk;
                pk.h2[0] = __floats2half2_rn(acc[j][0], acc[j][1]);
                pk.h2[1] = __floats2half2_rn(acc[j][2], acc[j][3]);
                *(uint2*)&g[(size_t)n * HD + c0] = pk.u;
                if ((cq & 3) == 0) {
                    a_src[(size_t)n * H_HEADS + head] = ps;
                    a_dst[(size_t)n * H_HEADS + head] = pd;
                }
            }
        }
    }
}

// ---------------------------------------------------------------------------
// CSR build: histogram -> 3-phase multi-block scan -> scatter.
// ---------------------------------------------------------------------------
__global__ __launch_bounds__(256) void hist_kernel(
        const int* __restrict__ ei, int* __restrict__ deg) {
    int e = blockIdx.x * 256 + threadIdx.x;
    if (e < E_EDGES) atomicAdd(&deg[ei[E_EDGES + e]], 1);
}

__global__ __launch_bounds__(SCAN_T) void block_sum_kernel(
        const int* __restrict__ deg, int* __restrict__ bsum) {
    int b = blockIdx.x, t = threadIdx.x;
    int lo = b * SCAN_CH, hi = min(lo + SCAN_CH, N_NODES);
    int s = 0;
    for (int i = lo + t; i < hi; i += SCAN_T) s += deg[i];
    #pragma unroll
    for (int m = 1; m < 64; m <<= 1) s += __shfl_xor(s, m);
    __shared__ int ws[SCAN_T / 64];
    if ((t & 63) == 0) ws[t >> 6] = s;
    __syncthreads();
    if (t == 0) {
        int tot = 0;
        #pragma unroll
        for (int w = 0; w < SCAN_T / 64; ++w) tot += ws[w];
        bsum[b] = tot;
    }
}

__global__ __launch_bounds__(SCAN_BLOCKS) void offset_scan_kernel(
        const int* __restrict__ bsum, int* __restrict__ boff) {
    __shared__ int tmp[SCAN_BLOCKS];
    int t = threadIdx.x;
    int v = bsum[t];
    tmp[t] = v;
    __syncthreads();
    int val = v;
    for (int off = 1; off < SCAN_BLOCKS; off <<= 1) {
        int o = (t >= off) ? tmp[t - off] : 0;
        __syncthreads();
        val += o;
        tmp[t] = val;
        __syncthreads();
    }
    boff[t] = val - v;    // exclusive
}

__global__ __launch_bounds__(SCAN_T) void row_ptr_kernel(
        const int* __restrict__ deg, const int* __restrict__ boff,
        int* __restrict__ row_ptr, int* __restrict__ fill) {
    int b = blockIdx.x, t = threadIdx.x;
    int lo = b * SCAN_CH, hi = min(lo + SCAN_CH, N_NODES);
    __shared__ int tmp[SCAN_T];
    __shared__ int carry;
    if (t == 0) carry = boff[b];
    __syncthreads();
    for (int base = lo; base < hi; base += SCAN_T) {
        int i = base + t;
        int v = (i < hi) ? deg[i] : 0;
        tmp[t] = v;
        __syncthreads();
        int val = v;
        for (int off = 1; off < SCAN_T; off <<= 1) {
            int o = (t >= off) ? tmp[t - off] : 0;
            __syncthreads();
            val += o;
            tmp[t] = val;
            __syncthreads();
        }
        int excl = val - v + carry;
        if (i < hi) { row_ptr[i] = excl; fill[i] = excl; }
        __syncthreads();
        if (t == SCAN_T - 1) carry = carry + val;
        __syncthreads();
    }
    if (b == SCAN_BLOCKS - 1 && t == 0) row_ptr[N_NODES] = carry;  // == E
}

__global__ __launch_bounds__(256) void scatter_kernel(
        const int* __restrict__ ei, int* __restrict__ fill,
        int* __restrict__ col) {
    int e = blockIdx.x * 256 + threadIdx.x;
    if (e < E_EDGES) {
        int d = ei[E_EDGES + e];
        int p = atomicAdd(&fill[d], 1);
        col[p] = ei[e];
    }
}

// ---------------------------------------------------------------------------
// Fused GAT aggregation over CSR, v2: FOUR dst per wave (one per 16-lane
// group). Each group owns its dst completely: 16 lanes x 8 channels = 128,
// group-local a_dst, self-loop folded into accumulator init, den computed
// redundantly per lane -> NO cross-group reduction, NO 64-slot preload
// waste (loop runs to max(deg) of 4 dsts, ~20% slack vs round 7-9's 47%).
// Col window refilled coalesced every 16 steps; unroll x2 -> 8 independent
// row gathers in flight per wave. Epilogue serves 4 dsts per wave with
// width-16 reductions.
// ---------------------------------------------------------------------------
template<bool FUSE>
__global__ __launch_bounds__(256) void gat_aggr_csr_kernel(
        const int* __restrict__ row_ptr, const int* __restrict__ col,
        const float* __restrict__ a_src, const float* __restrict__ a_dst,
        const __half* __restrict__ g, const float* __restrict__ bias,
        float* __restrict__ out,
        const float* __restrict__ Wy1, const float* __restrict__ by1,
        const float* __restrict__ Wy0, const float* __restrict__ by0,
        const float* __restrict__ Wc1, const float* __restrict__ bc1,
        const float* __restrict__ Wc2, const float* __restrict__ bc2) {
    int wv = threadIdx.x >> 6, lane = threadIdx.x & 63;
    int grp = lane >> 4;                 // dst slot within wave
    int sub = lane & 15;                 // channel slice (8*sub..8*sub+7)
    int hh  = sub >> 1;                  // head 0..7
    int d = blockIdx.x * 16 + wv * 4 + grp;
    bool dvalid = d < N_NODES;
    int dd = dvalid ? d : N_NODES - 1;

    int i0 = row_ptr[dd], end = row_ptr[dd + 1];
    int deg = dvalid ? (end - i0) : 0;
    float ad = a_dst[dd * 8 + hh];

    // self-loop folded into accumulator init (group-local, no reduction)
    float acc[8];
    float den;
    {
        float a = a_src[dd * 8 + hh] + ad;
        a = fmaxf(a, NEG_SLOPE * a);
        float w = __expf(a);
        uint4 rv = *(const uint4*)(g + (size_t)dd * HD + (sub << 3));
        float2 f0 = __half22float2(*(__half2*)&rv.x);
        float2 f1 = __half22float2(*(__half2*)&rv.y);
        float2 f2 = __half22float2(*(__half2*)&rv.z);
        float2 f3 = __half22float2(*(__half2*)&rv.w);
        acc[0] = w * f0.x; acc[1] = w * f0.y;
        acc[2] = w * f1.x; acc[3] = w * f1.y;
        acc[4] = w * f2.x; acc[5] = w * f2.y;
        acc[6] = w * f3.x; acc[7] = w * f3.y;
        den = w;
    }

    // wave-uniform loop bound: max degree over the wave's 4 dsts
    int md = deg;
    md = max(md, __shfl_xor(md, 16));
    md = max(md, __shfl_xor(md, 32));

    int colv = 0;
    #define EDGE_K(EL)                                                       \
    {                                                                        \
        int el_ = (EL);                                                      \
        int s = __shfl(colv, (grp << 4) | (el_ & 15));                       \
        float a = a_src[s * 8 + hh] + ad;                                    \
        a = fmaxf(a, NEG_SLOPE * a);                                         \
        float w = (el_ < deg) ? __expf(a) : 0.f;                             \
        uint4 rv = *(const uint4*)(g + (size_t)s * HD + (sub << 3));         \
        float2 f0 = __half22float2(*(__half2*)&rv.x);                        \
        float2 f1 = __half22float2(*(__half2*)&rv.y);                        \
        float2 f2 = __half22float2(*(__half2*)&rv.z);                        \
        float2 f3 = __half22float2(*(__half2*)&rv.w);                        \
        acc[0] += w * f0.x; acc[1] += w * f0.y;                              \
        acc[2] += w * f1.x; acc[3] += w * f1.y;                              \
        acc[4] += w * f2.x; acc[5] += w * f2.y;                              \
        acc[6] += w * f3.x; acc[7] += w * f3.y;                              \
        den += w;                                                            \
    }

    for (int el = 0; el < md; el += 2) {
        if ((el & 15) == 0) {             // coalesced window refill (uniform)
            int ci = i0 + el + sub;
            ci = min(ci, end - 1);
            ci = max(ci, 0);
            colv = col[ci];
        }
        EDGE_K(el);
        EDGE_K(el + 1);
    }
    #undef EDGE_K

    float inv = 1.f / (den + 1e-16f);
    int c0 = sub << 3;
    float h[8];
    #pragma unroll
    for (int k = 0; k < 8; ++k) h[k] = acc[k] * inv + bias[c0 + k];

    if (!FUSE) {
        if (dvalid) {
            *(float4*)&out[(size_t)d * HD + c0] =
                make_float4(h[0], h[1], h[2], h[3]);
            *(float4*)&out[(size_t)d * HD + c0 + 4] =
                make_float4(h[4], h[5], h[6], h[7]);
        }
    } else {
        // causal effect: width-16 reduction within the group
        float p = 0.f;
        #pragma unroll
        for (int k = 0; k < 8; ++k)
            p += h[k] * (Wy1[c0 + k] - Wy0[c0 + k]);
        p += __shfl_xor(p, 1); p += __shfl_xor(p, 2);
        p += __shfl_xor(p, 4); p += __shfl_xor(p, 8);
        // classifier MLP
        float acc2 = 0.f;
        #pragma unroll
        for (int j = 0; j < D_DIM; ++j) {
            float q = 0.f;
            #pragma unroll
            for (int k = 0; k < 8; ++k)
                q += h[k] * Wc1[(c0 + k) * D_DIM + j];
            q += __shfl_xor(q, 1); q += __shfl_xor(q, 2);
            q += __shfl_xor(q, 4); q += __shfl_xor(q, 8);
            float z = q + bc1[j];
            z = (z > 0.f) ? z : 0.f;
            acc2 += z * Wc2[j];
        }
        if (sub == 0 && dvalid) {
            out[d] = p + by1[0] - by0[0];
            out[N_NODES + d] = 1.f / (1.f + __expf(-(acc2 + bc2[0])));
        }
    }
}

// ---------------------------------------------------------------------------
extern "C" void kernel_launch(void* const* d_in, const int* in_sizes, int n_in,
                              void* d_out, int out_size, void* d_ws, size_t ws_size,
                              hipStream_t stream) {
    const float* x     = (const float*)d_in[0];
    const int*   ei    = (const int*)  d_in[1];
    const float* W_emb = (const float*)d_in[2];
    const float* b_emb = (const float*)d_in[3];
    const float* W0    = (const float*)d_in[4];
    const float* as0   = (const float*)d_in[5];
    const float* ad0   = (const float*)d_in[6];
    const float* b0    = (const float*)d_in[7];
    const float* W1    = (const float*)d_in[8];
    const float* as1   = (const float*)d_in[9];
    const float* ad1   = (const float*)d_in[10];
    const float* b1    = (const float*)d_in[11];
    const float* Wy1   = (const float*)d_in[12];
    const float* by1   = (const float*)d_in[13];
    const float* Wy0   = (const float*)d_in[14];
    const float* by0   = (const float*)d_in[15];
    const float* Wc1   = (const float*)d_in[16];
    const float* bc1   = (const float*)d_in[17];
    const float* Wc2   = (const float*)d_in[18];
    const float* bc2   = (const float*)d_in[19];
    float* out = (float*)d_out;

    float* ws    = (float*)d_ws;
    __half* gH   = (__half*)ws;                          // N*128 halves (25.6MB)
    float* bufH  = (float*)(ws + (size_t)N_NODES * HD / 2 + 64);  // N*128 f32
    float* h0    = bufH + (size_t)N_NODES * HD;          // N*16
    float* a_s   = h0   + (size_t)N_NODES * D_DIM;       // N*8
    float* a_d   = a_s  + (size_t)N_NODES * H_HEADS;     // N*8
    int*   deg     = (int*)(a_d + (size_t)N_NODES * H_HEADS);  // N
    int*   fill    = deg + N_NODES;                            // N
    int*   row_ptr = fill + N_NODES;                           // N+1
    int*   bsum    = row_ptr + (N_NODES + 1);                  // 256
    int*   boff    = bsum + SCAN_BLOCKS;                       // 256
    int*   col     = boff + SCAN_BLOCKS;                       // E

    int edgeBlocks = (E_EDGES + 255) / 256;
    int aggrBlocks = (N_NODES + 15) / 16;

    // ----- CSR build (once; reused by both layers) -----
    hipMemsetAsync(deg, 0, (size_t)N_NODES * sizeof(int), stream);
    hipLaunchKernelGGL(hist_kernel, dim3(edgeBlocks), dim3(256), 0, stream, ei, deg);
    hipLaunchKernelGGL(block_sum_kernel, dim3(SCAN_BLOCKS), dim3(SCAN_T), 0, stream,
                       deg, bsum);
    hipLaunchKernelGGL(offset_scan_kernel, dim3(1), dim3(SCAN_BLOCKS), 0, stream,
                       bsum, boff);
    hipLaunchKernelGGL(row_ptr_kernel, dim3(SCAN_BLOCKS), dim3(SCAN_T), 0, stream,
                       deg, boff, row_ptr, fill);
    hipLaunchKernelGGL(scatter_kernel, dim3(edgeBlocks), dim3(256), 0, stream,
                       ei, fill, col);

    // ----- Embedding -----
    hipLaunchKernelGGL(embed_kernel, dim3(512), dim3(256), 0, stream,
                       x, W_emb, b_emb, h0);

    // ----- GAT layer 0 (K = 16) -----
    hipLaunchKernelGGL(transform_gemm_kernel<16>, dim3(2048), dim3(256), 0, stream,
                       h0, W0, as0, ad0, gH, a_s, a_d);
    hipLaunchKernelGGL(gat_aggr_csr_kernel<false>, dim3(aggrBlocks), dim3(256), 0, stream,
                       row_ptr, col, a_s, a_d, gH, b0, bufH,
                       (const float*)nullptr, (const float*)nullptr,
                       (const float*)nullptr, (const float*)nullptr,
                       (const float*)nullptr, (const float*)nullptr,
                       (const float*)nullptr, (const float*)nullptr);

    // ----- GAT layer 1 (K = 128) + fused heads -----
    hipLaunchKernelGGL(transform_gemm_kernel<128>, dim3(1024), dim3(256), 0, stream,
                       bufH, W1, as1, ad1, gH, a_s, a_d);
    hipLaunchKernelGGL(gat_aggr_csr_kernel<true>, dim3(aggrBlocks), dim3(256), 0, stream,
                       row_ptr, col, a_s, a_d, gH, b1, out,
                       Wy1, by1, Wy0, by0, Wc1, bc1, Wc2, bc2);
}